// Round 1
// baseline (30970.905 us; speedup 1.0000x reference)
//
#include <hip/hip_runtime.h>
#include <hip/hip_bf16.h>
#include <math.h>

#define B_ 4
#define T_ 1024
#define D_ 1024
#define H_ 16
#define L_ 12
#define V_ 1025
#define DH_ 64
#define M_ (B_ * T_)  // 4096 rows

// ---------------- embedding: x = tok_emb[idx] + pos_emb ----------------
__global__ __launch_bounds__(256) void embed_k(const int* __restrict__ idx,
                                               const float* __restrict__ tok,
                                               const float* __restrict__ pos,
                                               float* __restrict__ x) {
  int bt = blockIdx.x;
  int t = bt & (T_ - 1);
  int token = idx[bt];
  float4 a = ((const float4*)(tok + (size_t)token * D_))[threadIdx.x];
  float4 p = ((const float4*)(pos + (size_t)t * D_))[threadIdx.x];
  float4 o;
  o.x = a.x + p.x; o.y = a.y + p.y; o.z = a.z + p.z; o.w = a.w + p.w;
  ((float4*)(x + (size_t)bt * D_))[threadIdx.x] = o;
}

// ---------------- LayerNorm (one block per row, D=1024) ----------------
__global__ __launch_bounds__(256) void ln_k(const float* __restrict__ x,
                                            const float* __restrict__ g,
                                            const float* __restrict__ b,
                                            float* __restrict__ o) {
  int row = blockIdx.x;
  int tid = threadIdx.x;
  float4 xv = ((const float4*)(x + (size_t)row * D_))[tid];
  float s = xv.x + xv.y + xv.z + xv.w;
  float ss = xv.x * xv.x + xv.y * xv.y + xv.z * xv.z + xv.w * xv.w;
#pragma unroll
  for (int off = 32; off; off >>= 1) {
    s += __shfl_xor(s, off);
    ss += __shfl_xor(ss, off);
  }
  __shared__ float rs[4], rss[4];
  int wid = tid >> 6, lane = tid & 63;
  if (lane == 0) { rs[wid] = s; rss[wid] = ss; }
  __syncthreads();
  s = rs[0] + rs[1] + rs[2] + rs[3];
  ss = rss[0] + rss[1] + rss[2] + rss[3];
  float mean = s * (1.0f / D_);
  float var = ss * (1.0f / D_) - mean * mean;
  float rstd = rsqrtf(var + 1e-5f);
  float4 gv = ((const float4*)g)[tid];
  float4 bv = ((const float4*)b)[tid];
  float4 ov;
  ov.x = (xv.x - mean) * rstd * gv.x + bv.x;
  ov.y = (xv.y - mean) * rstd * gv.y + bv.y;
  ov.z = (xv.z - mean) * rstd * gv.z + bv.z;
  ov.w = (xv.w - mean) * rstd * gv.w + bv.w;
  ((float4*)(o + (size_t)row * D_))[tid] = ov;
}

// ---------------- fp32 tiled GEMM: C = [res +] act(A@W + bias) ----------------
// A: [M,K] row-major, W: [K,N] row-major, bias: [N], res/C: [M,N]
__device__ __forceinline__ float gelu_f(float x) {
  return 0.5f * x * (1.0f + erff(x * 0.70710678118654752f));
}

template <int ACT, bool BIAS, bool RES>
__global__ __launch_bounds__(256) void gemm_f32(
    const float* __restrict__ A, const float* __restrict__ W,
    const float* __restrict__ bias, const float* __restrict__ res,
    float* __restrict__ C, int M, int N, int K) {
  __shared__ float As[16][68];  // A^T tile: As[k][m], padded
  __shared__ float Bs[16][64];  // Bs[k][n]
  int tid = threadIdx.x;
  int tx = tid & 15, ty = tid >> 4;
  int n0 = blockIdx.x * 64, m0 = blockIdx.y * 64;
  int a_m = tid >> 2, a_k = (tid & 3) << 2;
  int w_k = tid >> 4, w_n = (tid & 15) << 2;
  float acc[4][4] = {};
  for (int k0 = 0; k0 < K; k0 += 16) {
    float4 av = *(const float4*)(A + (size_t)(m0 + a_m) * K + k0 + a_k);
    float4 wv = *(const float4*)(W + (size_t)(k0 + w_k) * N + n0 + w_n);
    As[a_k + 0][a_m] = av.x;
    As[a_k + 1][a_m] = av.y;
    As[a_k + 2][a_m] = av.z;
    As[a_k + 3][a_m] = av.w;
    *(float4*)&Bs[w_k][w_n] = wv;
    __syncthreads();
#pragma unroll
    for (int kk = 0; kk < 16; ++kk) {
      float4 a4 = *(const float4*)&As[kk][ty << 2];
      float4 b4 = *(const float4*)&Bs[kk][tx << 2];
      float aa[4] = {a4.x, a4.y, a4.z, a4.w};
      float bb[4] = {b4.x, b4.y, b4.z, b4.w};
#pragma unroll
      for (int i = 0; i < 4; ++i)
#pragma unroll
        for (int j = 0; j < 4; ++j) acc[i][j] += aa[i] * bb[j];
    }
    __syncthreads();
  }
#pragma unroll
  for (int i = 0; i < 4; ++i) {
    size_t m = m0 + (ty << 2) + i;
    size_t off = m * N + n0 + (tx << 2);
    float4 r4;
    float* rv = &r4.x;
#pragma unroll
    for (int j = 0; j < 4; ++j) {
      float v = acc[i][j];
      if (BIAS) v += bias[n0 + (tx << 2) + j];
      if (ACT == 1) v = gelu_f(v);
      if (RES) v += res[off + j];
      rv[j] = v;
    }
    *(float4*)(C + off) = r4;
  }
}

// ---------------- flash attention (full, no mask), fp32 ----------------
// q,k,v,y: [B,T,D] with D = H*DH; one block = (b,h) x 16 query rows.
__global__ __launch_bounds__(256) void attn_k(const float* __restrict__ q,
                                              const float* __restrict__ kk,
                                              const float* __restrict__ vv,
                                              float* __restrict__ y) {
  int bh = blockIdx.x;
  int b = bh >> 4, h = bh & 15;
  int qb = blockIdx.y * 16;
  int tid = threadIdx.x, lane = tid & 63, wid = tid >> 6;
  __shared__ float Qs[16][64];
  __shared__ float Ks[64][65];  // padded: lane-indexed rows conflict-free
  __shared__ float Vs[64][64];
  size_t base = (size_t)b * T_ * D_ + h * DH_;
  {
    int r = tid >> 4, c = (tid & 15) << 2;
    *(float4*)&Qs[r][c] = *(const float4*)(q + base + (size_t)(qb + r) * D_ + c);
  }
  float acc[4] = {0.f, 0.f, 0.f, 0.f};
  float mr[4] = {-INFINITY, -INFINITY, -INFINITY, -INFINITY};
  float lr[4] = {0.f, 0.f, 0.f, 0.f};
  const float scale = 0.125f;  // 1/sqrt(64)
  for (int s0 = 0; s0 < T_; s0 += 64) {
    __syncthreads();  // Qs ready (iter 0) / prev tile reads done
    int r = tid >> 4, c = (tid & 15) << 2;
#pragma unroll
    for (int rr = 0; rr < 64; rr += 16) {
      float4 k4 = *(const float4*)(kk + base + (size_t)(s0 + r + rr) * D_ + c);
      Ks[r + rr][c + 0] = k4.x;
      Ks[r + rr][c + 1] = k4.y;
      Ks[r + rr][c + 2] = k4.z;
      Ks[r + rr][c + 3] = k4.w;
      float4 v4 = *(const float4*)(vv + base + (size_t)(s0 + r + rr) * D_ + c);
      *(float4*)&Vs[r + rr][c] = v4;
    }
    __syncthreads();
    // scores: lane `lane` owns key row s0+lane, for the wave's 4 query rows
    float sc[4] = {0.f, 0.f, 0.f, 0.f};
#pragma unroll
    for (int d = 0; d < 64; ++d) {
      float kd = Ks[lane][d];
      sc[0] += Qs[(wid << 2) + 0][d] * kd;
      sc[1] += Qs[(wid << 2) + 1][d] * kd;
      sc[2] += Qs[(wid << 2) + 2][d] * kd;
      sc[3] += Qs[(wid << 2) + 3][d] * kd;
    }
#pragma unroll
    for (int i = 0; i < 4; ++i) {
      float s = sc[i] * scale;
      float mt = s;
#pragma unroll
      for (int off = 32; off; off >>= 1) mt = fmaxf(mt, __shfl_xor(mt, off));
      float mnew = fmaxf(mr[i], mt);
      float p = __expf(s - mnew);
      float ps = p;
#pragma unroll
      for (int off = 32; off; off >>= 1) ps += __shfl_xor(ps, off);
      float corr = __expf(mr[i] - mnew);
      lr[i] = lr[i] * corr + ps;
      acc[i] *= corr;
      mr[i] = mnew;
#pragma unroll
      for (int s2 = 0; s2 < 64; ++s2) {
        acc[i] += __shfl(p, s2) * Vs[s2][lane];  // compile-time lane -> readlane
      }
    }
  }
#pragma unroll
  for (int i = 0; i < 4; ++i) {
    int row = qb + (wid << 2) + i;
    y[base + (size_t)row * D_ + lane] = acc[i] / lr[i];
  }
}

// ---------------- driver ----------------
extern "C" void kernel_launch(void* const* d_in, const int* in_sizes, int n_in,
                              void* d_out, int out_size, void* d_ws,
                              size_t ws_size, hipStream_t stream) {
  const int* idx = (const int*)d_in[0];
  const float* tok = (const float*)d_in[1];
  const float* pos = (const float*)d_in[2];
  const float* ln1g = (const float*)d_in[3];
  const float* ln1b = (const float*)d_in[4];
  const float* Wqkv = (const float*)d_in[5];
  const float* bqkv = (const float*)d_in[6];
  const float* Wp = (const float*)d_in[7];
  const float* bp = (const float*)d_in[8];
  const float* ln2g = (const float*)d_in[9];
  const float* ln2b = (const float*)d_in[10];
  const float* W1 = (const float*)d_in[11];
  const float* b1 = (const float*)d_in[12];
  const float* W2 = (const float*)d_in[13];
  const float* b2 = (const float*)d_in[14];
  const float* lnfg = (const float*)d_in[15];
  const float* lnfb = (const float*)d_in[16];
  const float* hW = (const float*)d_in[17];
  float* out = (float*)d_out;

  const size_t SZ = (size_t)M_ * D_;  // 4M floats
  float* x = (float*)d_ws;
  float* h = x + SZ;
  float* qb_ = h + SZ;
  float* kb_ = qb_ + SZ;
  float* vb_ = kb_ + SZ;
  float* yb_ = vb_ + SZ;
  float* tb_ = qb_;  // MLP mid [4096,4096] aliases q..y (free during MLP)

  embed_k<<<M_, 256, 0, stream>>>(idx, tok, pos, x);
  for (int l = 0; l < L_; ++l) {
    ln_k<<<M_, 256, 0, stream>>>(x, ln1g + (size_t)l * D_, ln1b + (size_t)l * D_, h);
    for (int c = 0; c < 3; ++c) {
      float* dst = (c == 0) ? qb_ : (c == 1) ? kb_ : vb_;
      gemm_f32<0, true, false><<<dim3(D_ / 64, M_ / 64), 256, 0, stream>>>(
          h, Wqkv + ((size_t)l * 3 + c) * D_ * D_, bqkv + ((size_t)l * 3 + c) * D_,
          nullptr, dst, M_, D_, D_);
    }
    attn_k<<<dim3(B_ * H_, T_ / 16), 256, 0, stream>>>(qb_, kb_, vb_, yb_);
    gemm_f32<0, true, true><<<dim3(D_ / 64, M_ / 64), 256, 0, stream>>>(
        yb_, Wp + (size_t)l * D_ * D_, bp + (size_t)l * D_, x, x, M_, D_, D_);
    ln_k<<<M_, 256, 0, stream>>>(x, ln2g + (size_t)l * D_, ln2b + (size_t)l * D_, h);
    gemm_f32<1, true, false><<<dim3(4 * D_ / 64, M_ / 64), 256, 0, stream>>>(
        h, W1 + (size_t)l * D_ * 4 * D_, b1 + (size_t)l * 4 * D_, nullptr, tb_,
        M_, 4 * D_, D_);
    gemm_f32<0, true, true><<<dim3(D_ / 64, M_ / 64), 256, 0, stream>>>(
        tb_, W2 + (size_t)l * 4 * D_ * D_, b2 + (size_t)l * D_, x, x, M_, D_,
        4 * D_);
  }
  ln_k<<<M_, 256, 0, stream>>>(x, lnfg, lnfb, h);
  gemm_f32<0, false, false><<<dim3((V_ - 1) / 64, M_ / 64), 256, 0, stream>>>(
      h, hW, nullptr, nullptr, out, M_, V_ - 1, D_);
}

// Round 2
// 17134.415 us; speedup vs baseline: 1.8075x; 1.8075x over previous
//
#include <hip/hip_runtime.h>
#include <math.h>

#define B_ 4
#define T_ 1024
#define D_ 1024
#define H_ 16
#define L_ 12
#define V_ 1025
#define DH_ 64
#define M_ (B_ * T_)  // 4096 rows
#define QS_ (3 * D_)  // fused qkv row stride

typedef unsigned short ushort_t;
typedef __attribute__((ext_vector_type(8))) short bf16x8;
typedef __attribute__((ext_vector_type(4))) float f32x4;

__device__ __forceinline__ ushort_t f2bf(float f) {
  unsigned int u = __float_as_uint(f);
  u += 0x7FFFu + ((u >> 16) & 1u);
  return (ushort_t)(u >> 16);
}

__device__ __forceinline__ void gload_lds16(const void* g, void* l) {
  __builtin_amdgcn_global_load_lds(
      (const __attribute__((address_space(1))) void*)g,
      (__attribute__((address_space(3))) void*)l, 16, 0, 0);
}

// ---------------- embedding: x = tok_emb[idx] + pos_emb (fp32) ----------------
__global__ __launch_bounds__(256) void embed_k(const int* __restrict__ idx,
                                               const float* __restrict__ tok,
                                               const float* __restrict__ pos,
                                               float* __restrict__ x) {
  int bt = blockIdx.x;
  int t = bt & (T_ - 1);
  int token = idx[bt];
  float4 a = ((const float4*)(tok + (size_t)token * D_))[threadIdx.x];
  float4 p = ((const float4*)(pos + (size_t)t * D_))[threadIdx.x];
  float4 o;
  o.x = a.x + p.x; o.y = a.y + p.y; o.z = a.z + p.z; o.w = a.w + p.w;
  ((float4*)(x + (size_t)bt * D_))[threadIdx.x] = o;
}

// ---------------- LayerNorm fp32 -> bf16 out ----------------
__global__ __launch_bounds__(256) void ln_k(const float* __restrict__ x,
                                            const float* __restrict__ g,
                                            const float* __restrict__ b,
                                            ushort_t* __restrict__ o) {
  int row = blockIdx.x;
  int tid = threadIdx.x;
  float4 xv = ((const float4*)(x + (size_t)row * D_))[tid];
  float s = xv.x + xv.y + xv.z + xv.w;
  float ss = xv.x * xv.x + xv.y * xv.y + xv.z * xv.z + xv.w * xv.w;
#pragma unroll
  for (int off = 32; off; off >>= 1) {
    s += __shfl_xor(s, off);
    ss += __shfl_xor(ss, off);
  }
  __shared__ float rs[4], rss[4];
  int wid = tid >> 6, lane = tid & 63;
  if (lane == 0) { rs[wid] = s; rss[wid] = ss; }
  __syncthreads();
  s = rs[0] + rs[1] + rs[2] + rs[3];
  ss = rss[0] + rss[1] + rss[2] + rss[3];
  float mean = s * (1.0f / D_);
  float var = ss * (1.0f / D_) - mean * mean;
  float rstd = rsqrtf(var + 1e-5f);
  float4 gv = ((const float4*)g)[tid];
  float4 bv = ((const float4*)b)[tid];
  ushort4 pk;
  pk.x = f2bf((xv.x - mean) * rstd * gv.x + bv.x);
  pk.y = f2bf((xv.y - mean) * rstd * gv.y + bv.y);
  pk.z = f2bf((xv.z - mean) * rstd * gv.z + bv.z);
  pk.w = f2bf((xv.w - mean) * rstd * gv.w + bv.w);
  *((ushort4*)(o + (size_t)row * D_) + tid) = pk;
}

// ---------------- transpose-cast: W fp32 [K,N] -> Wt bf16 [N,K] ----------------
__global__ __launch_bounds__(256) void tcast_k(const float* __restrict__ W,
                                               ushort_t* __restrict__ Wt,
                                               int K, int N) {
  __shared__ float s[32][33];
  int n0 = blockIdx.x * 32, k0 = blockIdx.y * 32;
  int tx = threadIdx.x & 31, ty = threadIdx.x >> 5;  // 8 rows of 32
#pragma unroll
  for (int i = 0; i < 4; ++i)
    s[ty + 8 * i][tx] = W[(size_t)(k0 + ty + 8 * i) * N + n0 + tx];  // s[k][n]
  __syncthreads();
#pragma unroll
  for (int i = 0; i < 4; ++i) {
    int n = ty + 8 * i;
    Wt[(size_t)(n0 + n) * K + k0 + tx] = f2bf(s[tx][n]);
  }
}

// ---------------- bf16 MFMA GEMM (m97 structure) ----------------
// A: [M,K] bf16, Bt: [N,K] bf16, C = [res +] act(A@B + bias)
__device__ __forceinline__ float gelu_f(float x) {
  return 0.5f * x * (1.0f + erff(x * 0.70710678118654752f));
}

template <int ACT, bool BIAS, bool RES, bool OBF16>
__global__ __launch_bounds__(256) void gemm_bf16(
    const ushort_t* __restrict__ A, const ushort_t* __restrict__ Bt,
    const float* __restrict__ bias, const float* __restrict__ res,
    void* __restrict__ Cout, int M, int N, int K) {
  __shared__ ushort_t As[128 * 64];  // [row][64] bf16, 128B rows
  __shared__ ushort_t Bs[128 * 64];
  int tid = threadIdx.x;
  int wid = tid >> 6, lane = tid & 63;
  int m0 = blockIdx.y * 128, n0 = blockIdx.x * 128;
  int wm = (wid >> 1) * 64, wn = (wid & 1) * 64;
  f32x4 acc[4][4] = {};
  for (int k0 = 0; k0 < K; k0 += 64) {
    __syncthreads();  // prev tile's ds_reads done before overwrite
#pragma unroll
    for (int i = 0; i < 4; ++i) {
      int cid = (wid * 4 + i) * 64 + lane;  // 16B chunk id, 0..1023
      int row = cid >> 3, c8 = cid & 7;
      gload_lds16(A + (size_t)(m0 + row) * K + k0 + c8 * 8,
                  As + (wid * 4 + i) * 512);
      gload_lds16(Bt + (size_t)(n0 + row) * K + k0 + c8 * 8,
                  Bs + (wid * 4 + i) * 512);
    }
    __syncthreads();  // staging complete (vmcnt drained by barrier)
#pragma unroll
    for (int ks = 0; ks < 2; ++ks) {
      int kb = ks * 32 + ((lane >> 4) << 3);
      bf16x8 a[4], b[4];
#pragma unroll
      for (int m = 0; m < 4; ++m)
        a[m] = *(const bf16x8*)(As + (wm + m * 16 + (lane & 15)) * 64 + kb);
#pragma unroll
      for (int n = 0; n < 4; ++n)
        b[n] = *(const bf16x8*)(Bs + (wn + n * 16 + (lane & 15)) * 64 + kb);
#pragma unroll
      for (int m = 0; m < 4; ++m)
#pragma unroll
        for (int n = 0; n < 4; ++n)
          acc[m][n] = __builtin_amdgcn_mfma_f32_16x16x32_bf16(a[m], b[n],
                                                              acc[m][n], 0, 0, 0);
    }
  }
  // epilogue: C[row = m0+wm+m*16+(lane>>4)*4+i][col = n0+wn+n*16+(lane&15)]
  float bias_v[4];
#pragma unroll
  for (int n = 0; n < 4; ++n) {
    if (BIAS) bias_v[n] = bias[n0 + wn + n * 16 + (lane & 15)];
    else bias_v[n] = 0.f;
  }
#pragma unroll
  for (int m = 0; m < 4; ++m) {
#pragma unroll
    for (int i = 0; i < 4; ++i) {
      size_t row = m0 + wm + m * 16 + ((lane >> 4) << 2) + i;
#pragma unroll
      for (int n = 0; n < 4; ++n) {
        size_t off = row * N + n0 + wn + n * 16 + (lane & 15);
        float v = acc[m][n][i] + bias_v[n];
        if (ACT == 1) v = gelu_f(v);
        if (RES) v += res[off];
        if (OBF16) ((ushort_t*)Cout)[off] = f2bf(v);
        else ((float*)Cout)[off] = v;
      }
    }
  }
}

// ---------------- flash attention fp32 (reads fused qkv, writes bf16) --------
__global__ __launch_bounds__(256) void attn_k(const float* __restrict__ qkv,
                                              ushort_t* __restrict__ y) {
  int bh = blockIdx.x;
  int b = bh >> 4, h = bh & 15;
  int qb = blockIdx.y * 16;
  int tid = threadIdx.x, lane = tid & 63, wid = tid >> 6;
  __shared__ float Qs[16][64];
  __shared__ float Ks[64][65];
  __shared__ float Vs[64][64];
  const float* qp = qkv + (size_t)b * T_ * QS_ + h * DH_;  // row t: qp[t*QS_ + ...]
  {
    int r = tid >> 4, c = (tid & 15) << 2;
    *(float4*)&Qs[r][c] = *(const float4*)(qp + (size_t)(qb + r) * QS_ + c);
  }
  float acc[4] = {0.f, 0.f, 0.f, 0.f};
  float mr[4] = {-INFINITY, -INFINITY, -INFINITY, -INFINITY};
  float lr[4] = {0.f, 0.f, 0.f, 0.f};
  const float scale = 0.125f;  // 1/sqrt(64)
  for (int s0 = 0; s0 < T_; s0 += 64) {
    __syncthreads();
    int r = tid >> 4, c = (tid & 15) << 2;
#pragma unroll
    for (int rr = 0; rr < 64; rr += 16) {
      float4 k4 = *(const float4*)(qp + (size_t)(s0 + r + rr) * QS_ + D_ + c);
      Ks[r + rr][c + 0] = k4.x;
      Ks[r + rr][c + 1] = k4.y;
      Ks[r + rr][c + 2] = k4.z;
      Ks[r + rr][c + 3] = k4.w;
      float4 v4 = *(const float4*)(qp + (size_t)(s0 + r + rr) * QS_ + 2 * D_ + c);
      *(float4*)&Vs[r + rr][c] = v4;
    }
    __syncthreads();
    float sc[4] = {0.f, 0.f, 0.f, 0.f};
#pragma unroll
    for (int d = 0; d < 64; ++d) {
      float kd = Ks[lane][d];
      sc[0] += Qs[(wid << 2) + 0][d] * kd;
      sc[1] += Qs[(wid << 2) + 1][d] * kd;
      sc[2] += Qs[(wid << 2) + 2][d] * kd;
      sc[3] += Qs[(wid << 2) + 3][d] * kd;
    }
#pragma unroll
    for (int i = 0; i < 4; ++i) {
      float s = sc[i] * scale;
      float mt = s;
#pragma unroll
      for (int off = 32; off; off >>= 1) mt = fmaxf(mt, __shfl_xor(mt, off));
      float mnew = fmaxf(mr[i], mt);
      float p = __expf(s - mnew);
      float ps = p;
#pragma unroll
      for (int off = 32; off; off >>= 1) ps += __shfl_xor(ps, off);
      float corr = __expf(mr[i] - mnew);
      lr[i] = lr[i] * corr + ps;
      acc[i] *= corr;
      mr[i] = mnew;
#pragma unroll
      for (int s2 = 0; s2 < 64; ++s2) {
        acc[i] += __shfl(p, s2) * Vs[s2][lane];
      }
    }
  }
#pragma unroll
  for (int i = 0; i < 4; ++i) {
    int row = qb + (wid << 2) + i;
    y[((size_t)b * T_ + row) * D_ + h * DH_ + lane] = f2bf(acc[i] / lr[i]);
  }
}

// ---------------- driver ----------------
extern "C" void kernel_launch(void* const* d_in, const int* in_sizes, int n_in,
                              void* d_out, int out_size, void* d_ws,
                              size_t ws_size, hipStream_t stream) {
  const int* idx = (const int*)d_in[0];
  const float* tok = (const float*)d_in[1];
  const float* pos = (const float*)d_in[2];
  const float* ln1g = (const float*)d_in[3];
  const float* ln1b = (const float*)d_in[4];
  const float* Wqkv = (const float*)d_in[5];
  const float* bqkv = (const float*)d_in[6];
  const float* Wp = (const float*)d_in[7];
  const float* bp = (const float*)d_in[8];
  const float* ln2g = (const float*)d_in[9];
  const float* ln2b = (const float*)d_in[10];
  const float* W1 = (const float*)d_in[11];
  const float* b1 = (const float*)d_in[12];
  const float* W2 = (const float*)d_in[13];
  const float* b2 = (const float*)d_in[14];
  const float* lnfg = (const float*)d_in[15];
  const float* lnfb = (const float*)d_in[16];
  const float* hW = (const float*)d_in[17];
  float* out = (float*)d_out;

  const size_t AM = (size_t)M_ * D_;  // 4M elements
  float* x = (float*)d_ws;            // 4M f32  (16 MB)
  float* qkv = x + AM;                // 12M f32 (48 MB)
  ushort_t* hb = (ushort_t*)(qkv + 3 * AM);  // 4M bf16 (8 MB)
  ushort_t* yb = hb + AM;                    // 4M bf16 (8 MB)
  ushort_t* Wt = yb + AM;                    // 4M bf16 (8 MB) weight scratch
  ushort_t* tb = (ushort_t*)qkv;             // MLP mid bf16 [4096][4096], aliases qkv

  embed_k<<<M_, 256, 0, stream>>>(idx, tok, pos, x);
  for (int l = 0; l < L_; ++l) {
    ln_k<<<M_, 256, 0, stream>>>(x, ln1g + (size_t)l * D_, ln1b + (size_t)l * D_, hb);
    for (int c = 0; c < 3; ++c)
      tcast_k<<<dim3(D_ / 32, D_ / 32), 256, 0, stream>>>(
          Wqkv + ((size_t)l * 3 + c) * D_ * D_, Wt + (size_t)c * D_ * D_, D_, D_);
    gemm_bf16<0, true, false, false><<<dim3(QS_ / 128, M_ / 128), 256, 0, stream>>>(
        hb, Wt, bqkv + (size_t)l * QS_, nullptr, qkv, M_, QS_, D_);
    attn_k<<<dim3(B_ * H_, T_ / 16), 256, 0, stream>>>(qkv, yb);
    tcast_k<<<dim3(D_ / 32, D_ / 32), 256, 0, stream>>>(Wp + (size_t)l * D_ * D_, Wt, D_, D_);
    gemm_bf16<0, true, true, false><<<dim3(D_ / 128, M_ / 128), 256, 0, stream>>>(
        yb, Wt, bp + (size_t)l * D_, x, x, M_, D_, D_);
    ln_k<<<M_, 256, 0, stream>>>(x, ln2g + (size_t)l * D_, ln2b + (size_t)l * D_, hb);
    tcast_k<<<dim3(4 * D_ / 32, D_ / 32), 256, 0, stream>>>(
        W1 + (size_t)l * D_ * 4 * D_, Wt, D_, 4 * D_);
    gemm_bf16<1, true, false, true><<<dim3(4 * D_ / 128, M_ / 128), 256, 0, stream>>>(
        hb, Wt, b1 + (size_t)l * 4 * D_, nullptr, tb, M_, 4 * D_, D_);
    tcast_k<<<dim3(D_ / 32, 4 * D_ / 32), 256, 0, stream>>>(
        W2 + (size_t)l * 4 * D_ * D_, Wt, 4 * D_, D_);
    gemm_bf16<0, true, true, false><<<dim3(D_ / 128, M_ / 128), 256, 0, stream>>>(
        tb, Wt, b2 + (size_t)l * D_, x, x, M_, D_, 4 * D_);
  }
  ln_k<<<M_, 256, 0, stream>>>(x, lnfg, lnfb, hb);
  tcast_k<<<dim3((V_ - 1) / 32, D_ / 32), 256, 0, stream>>>(hW, Wt, D_, V_ - 1);
  gemm_bf16<0, false, false, false><<<dim3((V_ - 1) / 128, M_ / 128), 256, 0, stream>>>(
      hb, Wt, nullptr, nullptr, out, M_, V_ - 1, D_);
}